// Round 3
// baseline (1256.435 us; speedup 1.0000x reference)
//
#include <hip/hip_runtime.h>

typedef unsigned short u16;
typedef __attribute__((ext_vector_type(8))) short bf16x8;
typedef __attribute__((ext_vector_type(4))) float f32x4;

#define MFMA16(a,b,c) __builtin_amdgcn_mfma_f32_16x16x32_bf16((a),(b),(c),0,0,0)

__device__ __forceinline__ float bf2f(u16 u){ union{unsigned int i; float f;} v; v.i=((unsigned int)u)<<16; return v.f; }
__device__ __forceinline__ u16 f2bf(float f){ union{float f; unsigned int i;} v; v.f=f; unsigned int r=v.i+0x7fffu+((v.i>>16)&1u); return (u16)(r>>16); }

// ============ K0: fp32 -> bf16 weight conversion (n multiple of 1024) ============
__global__ __launch_bounds__(256) void kcvt(const float* __restrict__ src, u16* __restrict__ dst, int n){
  int i = (blockIdx.x*256 + threadIdx.x)*4;
  if(i < n){
    float4 v = *(const float4*)(src + i);
    ushort4 o; o.x = f2bf(v.x); o.y = f2bf(v.y); o.z = f2bf(v.z); o.w = f2bf(v.w);
    *(ushort4*)(dst + i) = o;
  }
}

// ================= K1: qkvvT[b][oc][n] = sum_c Wq[oc][c]*x[b][c][n] (MFMA) =========
// A = Wqb (bf16 copy, L2-hot). B = x tile (fp32) transposed+converted into LDS.
#define K1PAD 136
__global__ __launch_bounds__(256) void k1_qkvv(const float* __restrict__ x, const u16* __restrict__ Wqb, u16* __restrict__ qkvvT){
  __shared__ u16 lB[128*K1PAD];
  const int tile = blockIdx.x;            // b*256 + token tile
  const int b  = tile >> 8;
  const int n0 = (tile & 255) << 7;
  const int oc0 = blockIdx.y << 7;
  const int tid = threadIdx.x;
  const float* xb = x + (size_t)b*128*32768;
  {
    const int cb = tid >> 4;
    const int t8 = (tid & 15) << 3;
    #pragma unroll
    for(int r=0;r<8;++r){
      int c = cb + (r<<4);
      const float4* p = (const float4*)(xb + (size_t)c*32768 + n0 + t8);
      float4 v0 = p[0], v1 = p[1];
      u16* d = &lB[0];
      d[(t8+0)*K1PAD + c] = f2bf(v0.x);
      d[(t8+1)*K1PAD + c] = f2bf(v0.y);
      d[(t8+2)*K1PAD + c] = f2bf(v0.z);
      d[(t8+3)*K1PAD + c] = f2bf(v0.w);
      d[(t8+4)*K1PAD + c] = f2bf(v1.x);
      d[(t8+5)*K1PAD + c] = f2bf(v1.y);
      d[(t8+6)*K1PAD + c] = f2bf(v1.z);
      d[(t8+7)*K1PAD + c] = f2bf(v1.w);
    }
  }
  __syncthreads();
  const int wave = tid >> 6, lane = tid & 63;
  const int wm = (wave & 1) << 6;   // oc half
  const int wn = (wave >> 1) << 6;  // token half
  const int lm = lane & 15, lq = lane >> 4;
  f32x4 acc[4][4] = {};
  const u16* Arow = Wqb + (oc0 + wm + lm)*128 + lq*8;
  #pragma unroll
  for(int ks=0; ks<4; ++ks){
    bf16x8 af[4], bfr[4];
    #pragma unroll
    for(int mt=0;mt<4;++mt) af[mt] = *(const bf16x8*)(Arow + mt*2048 + ks*32);
    #pragma unroll
    for(int nt=0;nt<4;++nt) bfr[nt] = *(const bf16x8*)(&lB[(wn + nt*16 + lm)*K1PAD + ks*32 + lq*8]);
    #pragma unroll
    for(int mt=0;mt<4;++mt)
      #pragma unroll
      for(int nt=0;nt<4;++nt)
        acc[mt][nt] = MFMA16(af[mt], bfr[nt], acc[mt][nt]);
  }
  u16* outb = qkvvT + (size_t)b*512*32768;
  #pragma unroll
  for(int mt=0;mt<4;++mt){
    const int ocr = oc0 + wm + mt*16 + lq*4;
    #pragma unroll
    for(int nt=0;nt<4;++nt){
      const int n = n0 + wn + nt*16 + lm;
      #pragma unroll
      for(int r=0;r<4;++r) outb[(size_t)(ocr+r)*32768 + n] = f2bf(acc[mt][nt][r]);
    }
  }
}

// ============ K2: fold fc(1x1) into depthwise-grouped conv weights (fp32 in) ======
// W_eff layout: [g 32][j 16][k 27][ol 4] fp32 ; oc = g*4+ol
__global__ void k2_weff(const float* __restrict__ Wdep, const float* __restrict__ Wfc,
                        const float* __restrict__ bdep, const float* __restrict__ bfc,
                        float* __restrict__ W_eff, float* __restrict__ bias_eff){
  int idx = blockIdx.x*256 + threadIdx.x;
  if(idx < 55296){
    int ol = idx & 3;
    int k  = (idx >> 2) % 27;
    int j  = (idx / 108) & 15;
    int g  = idx / 1728;
    int oc = g*4 + ol;
    float s = 0.f;
    for(int o=0;o<16;++o) s += Wdep[(oc*16 + o)*27 + k] * Wfc[o*16 + j];
    W_eff[idx] = s;
  }
  if(idx < 128){
    float s = bdep[idx];
    for(int o=0;o<16;++o){
      float wsum = 0.f;
      for(int k=0;k<27;++k) wsum += Wdep[(idx*16 + o)*27 + k];
      s += wsum * bfc[o];  // b_fc == 0 in this problem (boundary fold vacuous)
    }
    bias_eff[idx] = s;
  }
}

// ============ K2b: inverse l2 norms of q rows (c<128) and k rows (c 128..255) ====
__global__ __launch_bounds__(256) void k2b_norms(const u16* __restrict__ qkvvT, float* __restrict__ invn){
  const int b = blockIdx.x >> 8, c = blockIdx.x & 255;
  const u16* row = qkvvT + ((size_t)b*512 + c)*32768;
  float s = 0.f;
  for(int n = threadIdx.x*8; n < 32768; n += 2048){
    bf16x8 v = *(const bf16x8*)(row + n);
    #pragma unroll
    for(int j=0;j<8;++j){ float f = bf2f((u16)v[j]); s += f*f; }
  }
  for(int off=32; off; off>>=1) s += __shfl_down(s, off, 64);
  __shared__ float wsum[4];
  if((threadIdx.x & 63)==0) wsum[threadIdx.x>>6] = s;
  __syncthreads();
  if(threadIdx.x==0){
    float t = wsum[0]+wsum[1]+wsum[2]+wsum[3];
    invn[blockIdx.x] = 1.0f / fmaxf(sqrtf(t), 1e-12f);
  }
}

// ============ K3: k_proj / v_SA_proj = rows @ W_E^T  (MFMA, K split, atomics) ====
__global__ __launch_bounds__(256) void k3_proj(const u16* __restrict__ qkvvT, const u16* __restrict__ WEb,
                                               float* __restrict__ kp, float* __restrict__ vp){
  const int kc = blockIdx.x;            // K chunk of 1024
  const int b  = blockIdx.y;
  const int ts = blockIdx.z >> 1;       // 0: k, 1: v_SA
  const int rh = (blockIdx.z & 1) << 6; // row half
  const int wave = threadIdx.x >> 6, lane = threadIdx.x & 63;
  const int lm = lane & 15, lq = lane >> 4;
  const int coff = ts ? 384 : 128;
  const u16* Arow = qkvvT + ((size_t)b*512 + coff + rh + wave*16 + lm)*32768 + kc*1024 + lq*8;
  f32x4 acc[4] = {};
  for(int ks=0; ks<32; ++ks){
    bf16x8 af = *(const bf16x8*)(Arow + ks*32);
    #pragma unroll
    for(int nt=0;nt<4;++nt){
      bf16x8 bfr = *(const bf16x8*)(WEb + (size_t)(nt*16 + lm)*32768 + kc*1024 + ks*32 + lq*8);
      acc[nt] = MFMA16(af, bfr, acc[nt]);
    }
  }
  float* out = (ts ? vp : kp) + (size_t)b*128*64;
  const int r0 = rh + wave*16 + lq*4;
  #pragma unroll
  for(int nt=0;nt<4;++nt){
    const int p = nt*16 + lm;
    #pragma unroll
    for(int r=0;r<4;++r) atomicAdd(&out[(r0+r)*64 + p], acc[nt][r]);
  }
}

// ============ K4: Gram G[b,h][d][e] = sum_n q[d,n]k[e,n] (MFMA, K split) =========
__global__ __launch_bounds__(64) void k4_gram(const u16* __restrict__ qkvvT, float* __restrict__ G){
  const int kc = blockIdx.x, b = blockIdx.y, h = blockIdx.z;
  const int lane = threadIdx.x, lm = lane & 15, lq = lane >> 4;
  const u16* qb = qkvvT + ((size_t)b*512 + h*32)*32768 + kc*512 + lq*8;
  const u16* kb = qb + (size_t)128*32768;
  f32x4 acc[2][2] = {};
  for(int ks=0; ks<16; ++ks){
    bf16x8 af[2], bfr[2];
    af[0]  = *(const bf16x8*)(qb + (size_t)lm*32768 + ks*32);
    af[1]  = *(const bf16x8*)(qb + (size_t)(16+lm)*32768 + ks*32);
    bfr[0] = *(const bf16x8*)(kb + (size_t)lm*32768 + ks*32);
    bfr[1] = *(const bf16x8*)(kb + (size_t)(16+lm)*32768 + ks*32);
    #pragma unroll
    for(int mt=0;mt<2;++mt)
      #pragma unroll
      for(int nt=0;nt<2;++nt) acc[mt][nt] = MFMA16(af[mt], bfr[nt], acc[mt][nt]);
  }
  float* Gb = G + (size_t)(b*4 + h)*1024;
  #pragma unroll
  for(int mt=0;mt<2;++mt)
    #pragma unroll
    for(int nt=0;nt<2;++nt)
      #pragma unroll
      for(int r=0;r<4;++r){
        int d = mt*16 + lq*4 + r, e = nt*16 + lm;
        atomicAdd(&Gb[d*32 + e], acc[mt][nt][r]);
      }
}

// ============ K4b: scale+softmax(attn_CA) then M2 = W_out2 * attn_CA =============
__global__ __launch_bounds__(256) void k4b_softmax_m2(const float* __restrict__ G, const float* __restrict__ invn,
                                                      const float* __restrict__ temp, const float* __restrict__ Wout2,
                                                      u16* __restrict__ M2){
  const int b = blockIdx.x >> 2, h = blockIdx.x & 3;
  __shared__ float A[32][33];
  const float* Gb = G + (size_t)(b*4 + h)*1024;
  const float* inb = invn + b*256;
  const float th = temp[h];
  const int tid = threadIdx.x;
  if(tid < 32){
    const int d = tid;
    const float iq = inb[h*32 + d];
    float row[32]; float mx = -1e30f;
    #pragma unroll
    for(int e=0;e<32;++e){
      float v = Gb[d*32+e] * iq * inb[128 + h*32 + e] * th;
      row[e] = v; mx = fmaxf(mx, v);
    }
    float s = 0.f;
    #pragma unroll
    for(int e=0;e<32;++e){ float ee = __expf(row[e]-mx); row[e] = ee; s += ee; }
    const float rs = 1.0f/s;
    #pragma unroll
    for(int e=0;e<32;++e) A[d][e] = row[e]*rs;
  }
  __syncthreads();
  for(int o = tid; o < 2048; o += 256){
    const int j = o >> 5, e = o & 31;
    float s = 0.f;
    #pragma unroll
    for(int d=0;d<32;++d) s += Wout2[j*128 + h*32 + d] * A[d][e];
    M2[((size_t)b*64 + j)*128 + h*32 + e] = f2bf(s);
  }
}

// ============ K5: spatial (Linformer) attention per token -> xsa[b][h][d][n] =====
__global__ __launch_bounds__(256) void k5_xsa(const u16* __restrict__ qkvvT, const float* __restrict__ kp,
                                              const float* __restrict__ vp, const float* __restrict__ invn,
                                              const float* __restrict__ bE, const float* __restrict__ temp2,
                                              u16* __restrict__ xsa){
  const int b = blockIdx.z, h = blockIdx.y, n0 = blockIdx.x*256;
  __shared__ float lkp[32][64], lvp[32][64], liq[32];
  const int tid = threadIdx.x;
  for(int o = tid; o < 2048; o += 256){
    int d = o >> 6, p = o & 63;
    float be = bE[p];
    size_t base = ((size_t)b*128 + h*32 + d)*64 + p;
    lkp[d][p] = kp[base] + be;
    lvp[d][p] = vp[base] + be;
  }
  if(tid < 32) liq[tid] = invn[b*256 + h*32 + tid];
  __syncthreads();
  const int n = n0 + tid;
  const u16* qb = qkvvT + ((size_t)b*512 + h*32)*32768 + n;
  const float t2 = temp2[h];
  float s[64];
  #pragma unroll
  for(int p=0;p<64;++p) s[p]=0.f;
  for(int d=0; d<32; ++d){
    float qv = bf2f(qb[(size_t)d*32768]) * liq[d];
    #pragma unroll
    for(int p=0;p<64;++p) s[p] += qv * lkp[d][p];
  }
  float mx = -1e30f;
  #pragma unroll
  for(int p=0;p<64;++p){ s[p] *= t2; mx = fmaxf(mx, s[p]); }
  float sum = 0.f;
  #pragma unroll
  for(int p=0;p<64;++p){ s[p] = __expf(s[p]-mx); sum += s[p]; }
  const float r = 1.0f/sum;
  u16* ob = xsa + (((size_t)b*4 + h)*32)*32768 + n;
  for(int d=0; d<32; ++d){
    float acc = 0.f;
    #pragma unroll
    for(int p=0;p<64;++p) acc += s[p]*lvp[d][p];
    ob[(size_t)d*32768] = f2bf(acc*r);
  }
}

// ============ K_conv: fused grouped 3x3x3 conv (fc folded in), out [b][n][128] ====
__global__ __launch_bounds__(256) void kconv(const u16* __restrict__ qkvvT, const float* __restrict__ W_eff,
                                             const float* __restrict__ bias_eff, u16* __restrict__ convo){
  __shared__ u16 lf[8*10*10*34];
  __shared__ float lw[1728];
  __shared__ float lbias[4];
  const int zt = blockIdx.x >> 2, yt = blockIdx.x & 3;
  const int g = blockIdx.y, b = blockIdx.z;
  const int tid = threadIdx.x;
  for(int i = tid; i < 1728; i += 256) lw[i] = W_eff[g*1728 + i];
  if(tid < 4) lbias[tid] = bias_eff[g*4 + tid];
  const int z0 = zt << 3, y0 = yt << 3;
  const int vz = tid >> 5, vy = (tid >> 2) & 7, x0 = (tid & 3) << 3;
  float acc[4][8];
  #pragma unroll
  for(int o=0;o<4;++o)
    #pragma unroll
    for(int xi=0;xi<8;++xi) acc[o][xi] = 0.f;
  const u16* qb = qkvvT + (size_t)b*512*32768;
  for(int p=0;p<2;++p){
    __syncthreads();
    for(int idx = tid; idx < 27200; idx += 256){
      int jj = idx / 3400;
      int rem = idx - jj*3400;
      int z = rem / 340; rem -= z*340;
      int y = rem / 34;
      int xx = rem - y*34;
      int gz = z0 + z - 1, gy = y0 + y - 1, gx = xx - 1;
      u16 v = 0;
      if((unsigned)gz < 32u && (unsigned)gy < 32u && (unsigned)gx < 32u)
        v = qb[(size_t)((p*8+jj)*32 + g)*32768 + gz*1024 + gy*32 + gx];
      lf[idx] = v;
    }
    __syncthreads();
    for(int jj=0;jj<8;++jj){
      const int jglob = p*8 + jj;
      #pragma unroll
      for(int kz=0;kz<3;++kz){
        #pragma unroll
        for(int ky=0;ky<3;++ky){
          const int base = ((jj*10 + vz+kz)*10 + vy+ky)*34 + x0;
          const unsigned int* lp = (const unsigned int*)lf;
          float fw[10];
          #pragma unroll
          for(int t=0;t<5;++t){
            unsigned int u = lp[(base>>1) + t];
            union{unsigned int i; float f;} lo, hi;
            lo.i = u << 16; hi.i = u & 0xffff0000u;
            fw[2*t] = lo.f; fw[2*t+1] = hi.f;
          }
          const float4* w4 = (const float4*)&lw[(jglob*27 + (kz*3+ky)*3)*4];
          #pragma unroll
          for(int kx=0;kx<3;++kx){
            float4 wv = w4[kx];
            #pragma unroll
            for(int xi=0;xi<8;++xi){
              float f = fw[xi+kx];
              acc[0][xi] += wv.x*f;
              acc[1][xi] += wv.y*f;
              acc[2][xi] += wv.z*f;
              acc[3][xi] += wv.w*f;
            }
          }
        }
      }
    }
  }
  const int nb = (z0+vz)*1024 + (y0+vy)*32 + x0;
  u16* ob = convo + ((size_t)b*32768 + nb)*128 + g*4;
  #pragma unroll
  for(int xi=0;xi<8;++xi){
    unsigned long long pk = (unsigned long long)f2bf(acc[0][xi] + lbias[0])
                          | ((unsigned long long)f2bf(acc[1][xi] + lbias[1]) << 16)
                          | ((unsigned long long)f2bf(acc[2][xi] + lbias[2]) << 32)
                          | ((unsigned long long)f2bf(acc[3][xi] + lbias[3]) << 48);
    *(unsigned long long*)(ob + (size_t)xi*128) = pk;
  }
}

// ============ K6: output assembly (SA gather-GEMM + CA GEMM + conv + rates), fp32 out
#define K6PAD 136
__global__ __launch_bounds__(256) void k6_out(const u16* __restrict__ qkvvT, const u16* __restrict__ xsa,
                                              const u16* __restrict__ conv, const u16* __restrict__ M2,
                                              const u16* __restrict__ Woutb, const float* __restrict__ bout,
                                              const float* __restrict__ bout2, const float* __restrict__ rate,
                                              const float* __restrict__ rate2, float* __restrict__ out){
  __shared__ u16 lA[128*K6PAD];
  const int tile = blockIdx.x;
  const int b  = tile >> 8;
  const int n0 = (tile & 255) << 7;
  const int tid = threadIdx.x;
  const int hh = (n0 >> 8) & 3;   // constant per 128-token tile
  const int dh = n0 >> 10;
  // ---- phase A: stage scrambled x_SA segment (contiguous!) -> lA[tok][c']
  const u16* xseg = xsa + (((size_t)b*4 + hh)*32 + dh)*32768 + ((size_t)(n0 & 255) << 7);
  {
    const int r = tid >> 1, off = (tid & 1) << 6;
    const u16* src = xseg + r*128 + off;
    u16* dst = &lA[r*K6PAD + off];
    #pragma unroll
    for(int q=0;q<8;++q) *(bf16x8*)(dst + q*8) = *(const bf16x8*)(src + q*8);
  }
  __syncthreads();
  const int wave = tid >> 6, lane = tid & 63;
  const int lm = lane & 15, lq = lane >> 4;
  f32x4 accS[2][4] = {};
  #pragma unroll
  for(int ks=0;ks<4;++ks){
    bf16x8 a0 = *(const bf16x8*)(&lA[(wave*32 + lm)*K6PAD + ks*32 + lq*8]);
    bf16x8 a1 = *(const bf16x8*)(&lA[(wave*32 + 16 + lm)*K6PAD + ks*32 + lq*8]);
    #pragma unroll
    for(int nt=0;nt<4;++nt){
      bf16x8 bw = *(const bf16x8*)(Woutb + (nt*16 + lm)*128 + ks*32 + lq*8);
      accS[0][nt] = MFMA16(a0, bw, accS[0][nt]);
      accS[1][nt] = MFMA16(a1, bw, accS[1][nt]);
    }
  }
  __syncthreads();
  // ---- phase B: stage v_CA tile transposed -> lA[tok][c'']
  {
    const int cb = tid >> 4, t8 = (tid & 15) << 3;
    const u16* vb = qkvvT + ((size_t)b*512 + 256)*32768 + n0;
    #pragma unroll
    for(int r2=0;r2<8;++r2){
      int c = cb + (r2<<4);
      bf16x8 v = *(const bf16x8*)(vb + (size_t)c*32768 + t8);
      #pragma unroll
      for(int j=0;j<8;++j) lA[(t8+j)*K6PAD + c] = (u16)v[j];
    }
  }
  __syncthreads();
  f32x4 accC[2][4] = {};
  #pragma unroll
  for(int ks=0;ks<4;++ks){
    bf16x8 a0 = *(const bf16x8*)(&lA[(wave*32 + lm)*K6PAD + ks*32 + lq*8]);
    bf16x8 a1 = *(const bf16x8*)(&lA[(wave*32 + 16 + lm)*K6PAD + ks*32 + lq*8]);
    #pragma unroll
    for(int nt=0;nt<4;++nt){
      bf16x8 bm = *(const bf16x8*)(M2 + ((size_t)b*64 + nt*16 + lm)*128 + ks*32 + lq*8);
      accC[0][nt] = MFMA16(a0, bm, accC[0][nt]);
      accC[1][nt] = MFMA16(a1, bm, accC[1][nt]);
    }
  }
  const float rt = rate[0], rt2 = rate2[0];
  float* ob = out + ((size_t)b*32768 + n0)*128;
  const u16* cbp = conv + ((size_t)b*32768 + n0)*128;
  #pragma unroll
  for(int mt=0;mt<2;++mt){
    #pragma unroll
    for(int r=0;r<4;++r){
      const int tok = wave*32 + mt*16 + lq*4 + r;
      #pragma unroll
      for(int nt=0;nt<4;++nt){
        const int j = nt*16 + lm;
        float sa = accS[mt][nt][r] + bout[j];
        float ca = accC[mt][nt][r] + bout2[j];
        float c1 = bf2f(cbp[(size_t)tok*128 + j]);
        float c2 = bf2f(cbp[(size_t)tok*128 + 64 + j]);
        ob[(size_t)tok*128 + j]      = rt*sa + rt2*c1;
        ob[(size_t)tok*128 + 64 + j] = rt*ca + rt2*c2;
      }
    }
  }
}

extern "C" void kernel_launch(void* const* d_in, const int* in_sizes, int n_in,
                              void* d_out, int out_size, void* d_ws, size_t ws_size,
                              hipStream_t stream){
  const float* x     = (const float*)d_in[0];
  const float* Wq    = (const float*)d_in[1];
  const float* Wfc   = (const float*)d_in[2];
  const float* bfc   = (const float*)d_in[3];
  const float* Wdep  = (const float*)d_in[4];
  const float* bdep  = (const float*)d_in[5];
  const float* WE    = (const float*)d_in[6];
  const float* bE    = (const float*)d_in[7];
  const float* temp  = (const float*)d_in[8];
  const float* temp2 = (const float*)d_in[9];
  const float* rate  = (const float*)d_in[10];
  const float* rate2 = (const float*)d_in[11];
  const float* Wout  = (const float*)d_in[12];
  const float* bout  = (const float*)d_in[13];
  const float* Wout2 = (const float*)d_in[14];
  const float* bout2 = (const float*)d_in[15];
  float* outp = (float*)d_out;

  char* w = (char*)d_ws;
  size_t off = 0;
  auto alloc = [&](size_t bytes)->char*{ char* p = w + off; off += (bytes + 255) & ~(size_t)255; return p; };
  u16*   qkvvT  = (u16*)  alloc((size_t)4*512*32768*2);   // 134 MB, channel-major
  u16*   xsa    = (u16*)  alloc((size_t)4*4*32*32768*2);  // 33.5 MB
  u16*   convb  = (u16*)  alloc((size_t)4*32768*128*2);   // 33.5 MB, token-major
  float* W_eff  = (float*)alloc(55296*4);
  float* biasef = (float*)alloc(128*4);
  float* invn   = (float*)alloc(1024*4);
  float* kp     = (float*)alloc(32768*4);
  float* vp     = (float*)alloc(32768*4);
  float* G      = (float*)alloc(16384*4);
  u16*   M2     = (u16*)  alloc(32768*2);
  u16*   WEb    = (u16*)  alloc((size_t)2097152*2);       // bf16 copies of MFMA weights
  u16*   Wqb    = (u16*)  alloc(65536*2);
  u16*   Woutb  = (u16*)  alloc(8192*2);

  // zero the fp32 atomic-accumulation buffers (kp|vp|G are contiguous)
  hipMemsetAsync(kp, 0, (size_t)(32768+32768+16384)*4, stream);

  kcvt          <<<2048,          256, 0, stream>>>(WE,   WEb,   2097152);
  kcvt          <<<64,            256, 0, stream>>>(Wq,   Wqb,   65536);
  kcvt          <<<8,             256, 0, stream>>>(Wout, Woutb, 8192);
  k1_qkvv       <<<dim3(1024,4),  256, 0, stream>>>(x, Wqb, qkvvT);
  k2_weff       <<<216,           256, 0, stream>>>(Wdep, Wfc, bdep, bfc, W_eff, biasef);
  k2b_norms     <<<1024,          256, 0, stream>>>(qkvvT, invn);
  k3_proj       <<<dim3(32,4,4),  256, 0, stream>>>(qkvvT, WEb, kp, vp);
  k4_gram       <<<dim3(64,4,4),   64, 0, stream>>>(qkvvT, G);
  k4b_softmax_m2<<<16,            256, 0, stream>>>(G, invn, temp, Wout2, M2);
  k5_xsa        <<<dim3(128,4,4), 256, 0, stream>>>(qkvvT, kp, vp, invn, bE, temp2, xsa);
  kconv         <<<dim3(16,32,4), 256, 0, stream>>>(qkvvT, W_eff, biasef, convb);
  k6_out        <<<1024,          256, 0, stream>>>(qkvvT, xsa, convb, M2, Woutb, bout, bout2, rate, rate2, outp);
}

// Round 4
// 651.237 us; speedup vs baseline: 1.9293x; 1.9293x over previous
//
#include <hip/hip_runtime.h>

typedef unsigned short u16;
typedef __attribute__((ext_vector_type(8))) short bf16x8;
typedef __attribute__((ext_vector_type(4))) float f32x4;

#define MFMA16(a,b,c) __builtin_amdgcn_mfma_f32_16x16x32_bf16((a),(b),(c),0,0,0)

__device__ __forceinline__ float bf2f(u16 u){ union{unsigned int i; float f;} v; v.i=((unsigned int)u)<<16; return v.f; }
__device__ __forceinline__ u16 f2bf(float f){ union{float f; unsigned int i;} v; v.f=f; unsigned int r=v.i+0x7fffu+((v.i>>16)&1u); return (u16)(r>>16); }

// ============ K0: fp32 -> bf16 weight conversion (n multiple of 1024) ============
__global__ __launch_bounds__(256) void kcvt(const float* __restrict__ src, u16* __restrict__ dst, int n){
  int i = (blockIdx.x*256 + threadIdx.x)*4;
  if(i < n){
    float4 v = *(const float4*)(src + i);
    ushort4 o; o.x = f2bf(v.x); o.y = f2bf(v.y); o.z = f2bf(v.z); o.w = f2bf(v.w);
    *(ushort4*)(dst + i) = o;
  }
}

// ================= K1: qkvvT[b][oc][n] = sum_c Wq[oc][c]*x[b][c][n] (MFMA) =========
// A = Wqb (bf16 copy, L2-hot). B = x tile (fp32) transposed+converted into LDS.
// v2: all 4 oc-strips computed per block (x tile read once, not 4x).
#define K1PAD 136
__global__ __launch_bounds__(256) void k1_qkvv(const float* __restrict__ x, const u16* __restrict__ Wqb, u16* __restrict__ qkvvT){
  __shared__ u16 lB[128*K1PAD];
  const int tile = blockIdx.x;            // b*256 + token tile
  const int b  = tile >> 8;
  const int n0 = (tile & 255) << 7;
  const int tid = threadIdx.x;
  const float* xb = x + (size_t)b*128*32768;
  {
    const int cb = tid >> 4;
    const int t8 = (tid & 15) << 3;
    #pragma unroll
    for(int r=0;r<8;++r){
      int c = cb + (r<<4);
      const float4* p = (const float4*)(xb + (size_t)c*32768 + n0 + t8);
      float4 v0 = p[0], v1 = p[1];
      u16* d = &lB[0];
      d[(t8+0)*K1PAD + c] = f2bf(v0.x);
      d[(t8+1)*K1PAD + c] = f2bf(v0.y);
      d[(t8+2)*K1PAD + c] = f2bf(v0.z);
      d[(t8+3)*K1PAD + c] = f2bf(v0.w);
      d[(t8+4)*K1PAD + c] = f2bf(v1.x);
      d[(t8+5)*K1PAD + c] = f2bf(v1.y);
      d[(t8+6)*K1PAD + c] = f2bf(v1.z);
      d[(t8+7)*K1PAD + c] = f2bf(v1.w);
    }
  }
  __syncthreads();
  const int wave = tid >> 6, lane = tid & 63;
  const int wm = (wave & 1) << 6;   // oc half
  const int wn = (wave >> 1) << 6;  // token half
  const int lm = lane & 15, lq = lane >> 4;
  u16* outb = qkvvT + (size_t)b*512*32768;
  for(int s=0;s<4;++s){
    const int oc0 = s << 7;
    f32x4 acc[4][4] = {};
    const u16* Arow = Wqb + (oc0 + wm + lm)*128 + lq*8;
    #pragma unroll
    for(int ks=0; ks<4; ++ks){
      bf16x8 af[4], bfr[4];
      #pragma unroll
      for(int mt=0;mt<4;++mt) af[mt] = *(const bf16x8*)(Arow + mt*2048 + ks*32);
      #pragma unroll
      for(int nt=0;nt<4;++nt) bfr[nt] = *(const bf16x8*)(&lB[(wn + nt*16 + lm)*K1PAD + ks*32 + lq*8]);
      #pragma unroll
      for(int mt=0;mt<4;++mt)
        #pragma unroll
        for(int nt=0;nt<4;++nt)
          acc[mt][nt] = MFMA16(af[mt], bfr[nt], acc[mt][nt]);
    }
    #pragma unroll
    for(int mt=0;mt<4;++mt){
      const int ocr = oc0 + wm + mt*16 + lq*4;
      #pragma unroll
      for(int nt=0;nt<4;++nt){
        const int n = n0 + wn + nt*16 + lm;
        #pragma unroll
        for(int r=0;r<4;++r) outb[(size_t)(ocr+r)*32768 + n] = f2bf(acc[mt][nt][r]);
      }
    }
  }
}

// ============ K2: fold fc(1x1) into depthwise-grouped conv weights (fp32 in) ======
// W_eff layout: [g 32][j 16][k 27][ol 4] fp32 ; oc = g*4+ol
__global__ void k2_weff(const float* __restrict__ Wdep, const float* __restrict__ Wfc,
                        const float* __restrict__ bdep, const float* __restrict__ bfc,
                        float* __restrict__ W_eff, float* __restrict__ bias_eff){
  int idx = blockIdx.x*256 + threadIdx.x;
  if(idx < 55296){
    int ol = idx & 3;
    int k  = (idx >> 2) % 27;
    int j  = (idx / 108) & 15;
    int g  = idx / 1728;
    int oc = g*4 + ol;
    float s = 0.f;
    for(int o=0;o<16;++o) s += Wdep[(oc*16 + o)*27 + k] * Wfc[o*16 + j];
    W_eff[idx] = s;
  }
  if(idx < 128){
    float s = bdep[idx];
    for(int o=0;o<16;++o){
      float wsum = 0.f;
      for(int k=0;k<27;++k) wsum += Wdep[(idx*16 + o)*27 + k];
      s += wsum * bfc[o];  // b_fc == 0 in this problem (boundary fold vacuous)
    }
    bias_eff[idx] = s;
  }
}

// ============ K2b: inverse l2 norms of q rows (c<128) and k rows (c 128..255) ====
__global__ __launch_bounds__(256) void k2b_norms(const u16* __restrict__ qkvvT, float* __restrict__ invn){
  const int b = blockIdx.x >> 8, c = blockIdx.x & 255;
  const u16* row = qkvvT + ((size_t)b*512 + c)*32768;
  float s = 0.f;
  for(int n = threadIdx.x*8; n < 32768; n += 2048){
    bf16x8 v = *(const bf16x8*)(row + n);
    #pragma unroll
    for(int j=0;j<8;++j){ float f = bf2f((u16)v[j]); s += f*f; }
  }
  for(int off=32; off; off>>=1) s += __shfl_down(s, off, 64);
  __shared__ float wsum[4];
  if((threadIdx.x & 63)==0) wsum[threadIdx.x>>6] = s;
  __syncthreads();
  if(threadIdx.x==0){
    float t = wsum[0]+wsum[1]+wsum[2]+wsum[3];
    invn[blockIdx.x] = 1.0f / fmaxf(sqrtf(t), 1e-12f);
  }
}

// ============ K3: k_proj / v_SA_proj = rows @ W_E^T  (MFMA, K split, atomics) ====
__global__ __launch_bounds__(256) void k3_proj(const u16* __restrict__ qkvvT, const u16* __restrict__ WEb,
                                               float* __restrict__ kp, float* __restrict__ vp){
  const int kc = blockIdx.x;            // K chunk of 1024
  const int b  = blockIdx.y;
  const int ts = blockIdx.z >> 1;       // 0: k, 1: v_SA
  const int rh = (blockIdx.z & 1) << 6; // row half
  const int wave = threadIdx.x >> 6, lane = threadIdx.x & 63;
  const int lm = lane & 15, lq = lane >> 4;
  const int coff = ts ? 384 : 128;
  const u16* Arow = qkvvT + ((size_t)b*512 + coff + rh + wave*16 + lm)*32768 + kc*1024 + lq*8;
  f32x4 acc[4] = {};
  for(int ks=0; ks<32; ++ks){
    bf16x8 af = *(const bf16x8*)(Arow + ks*32);
    #pragma unroll
    for(int nt=0;nt<4;++nt){
      bf16x8 bfr = *(const bf16x8*)(WEb + (size_t)(nt*16 + lm)*32768 + kc*1024 + ks*32 + lq*8);
      acc[nt] = MFMA16(af, bfr, acc[nt]);
    }
  }
  float* out = (ts ? vp : kp) + (size_t)b*128*64;
  const int r0 = rh + wave*16 + lq*4;
  #pragma unroll
  for(int nt=0;nt<4;++nt){
    const int p = nt*16 + lm;
    #pragma unroll
    for(int r=0;r<4;++r) atomicAdd(&out[(r0+r)*64 + p], acc[nt][r]);
  }
}

// ============ K4: Gram G[b,h][d][e] = sum_n q[d,n]k[e,n] (MFMA, K split) =========
__global__ __launch_bounds__(64) void k4_gram(const u16* __restrict__ qkvvT, float* __restrict__ G){
  const int kc = blockIdx.x, b = blockIdx.y, h = blockIdx.z;
  const int lane = threadIdx.x, lm = lane & 15, lq = lane >> 4;
  const u16* qb = qkvvT + ((size_t)b*512 + h*32)*32768 + kc*512 + lq*8;
  const u16* kb = qb + (size_t)128*32768;
  f32x4 acc[2][2] = {};
  for(int ks=0; ks<16; ++ks){
    bf16x8 af[2], bfr[2];
    af[0]  = *(const bf16x8*)(qb + (size_t)lm*32768 + ks*32);
    af[1]  = *(const bf16x8*)(qb + (size_t)(16+lm)*32768 + ks*32);
    bfr[0] = *(const bf16x8*)(kb + (size_t)lm*32768 + ks*32);
    bfr[1] = *(const bf16x8*)(kb + (size_t)(16+lm)*32768 + ks*32);
    #pragma unroll
    for(int mt=0;mt<2;++mt)
      #pragma unroll
      for(int nt=0;nt<2;++nt) acc[mt][nt] = MFMA16(af[mt], bfr[nt], acc[mt][nt]);
  }
  float* Gb = G + (size_t)(b*4 + h)*1024;
  #pragma unroll
  for(int mt=0;mt<2;++mt)
    #pragma unroll
    for(int nt=0;nt<2;++nt)
      #pragma unroll
      for(int r=0;r<4;++r){
        int d = mt*16 + lq*4 + r, e = nt*16 + lm;
        atomicAdd(&Gb[d*32 + e], acc[mt][nt][r]);
      }
}

// ============ K4b: scale+softmax(attn_CA) then M2 = W_out2 * attn_CA =============
__global__ __launch_bounds__(256) void k4b_softmax_m2(const float* __restrict__ G, const float* __restrict__ invn,
                                                      const float* __restrict__ temp, const float* __restrict__ Wout2,
                                                      u16* __restrict__ M2){
  const int b = blockIdx.x >> 2, h = blockIdx.x & 3;
  __shared__ float A[32][33];
  const float* Gb = G + (size_t)(b*4 + h)*1024;
  const float* inb = invn + b*256;
  const float th = temp[h];
  const int tid = threadIdx.x;
  if(tid < 32){
    const int d = tid;
    const float iq = inb[h*32 + d];
    float row[32]; float mx = -1e30f;
    #pragma unroll
    for(int e=0;e<32;++e){
      float v = Gb[d*32+e] * iq * inb[128 + h*32 + e] * th;
      row[e] = v; mx = fmaxf(mx, v);
    }
    float s = 0.f;
    #pragma unroll
    for(int e=0;e<32;++e){ float ee = __expf(row[e]-mx); row[e] = ee; s += ee; }
    const float rs = 1.0f/s;
    #pragma unroll
    for(int e=0;e<32;++e) A[d][e] = row[e]*rs;
  }
  __syncthreads();
  for(int o = tid; o < 2048; o += 256){
    const int j = o >> 5, e = o & 31;
    float s = 0.f;
    #pragma unroll
    for(int d=0;d<32;++d) s += Wout2[j*128 + h*32 + d] * A[d][e];
    M2[((size_t)b*64 + j)*128 + h*32 + e] = f2bf(s);
  }
}

// ============ K5: spatial (Linformer) attention per token -> xsa[b][h][d][n] =====
__global__ __launch_bounds__(256) void k5_xsa(const u16* __restrict__ qkvvT, const float* __restrict__ kp,
                                              const float* __restrict__ vp, const float* __restrict__ invn,
                                              const float* __restrict__ bE, const float* __restrict__ temp2,
                                              u16* __restrict__ xsa){
  const int b = blockIdx.z, h = blockIdx.y, n0 = blockIdx.x*256;
  __shared__ float lkp[32][64], lvp[32][64], liq[32];
  const int tid = threadIdx.x;
  for(int o = tid; o < 2048; o += 256){
    int d = o >> 6, p = o & 63;
    float be = bE[p];
    size_t base = ((size_t)b*128 + h*32 + d)*64 + p;
    lkp[d][p] = kp[base] + be;
    lvp[d][p] = vp[base] + be;
  }
  if(tid < 32) liq[tid] = invn[b*256 + h*32 + tid];
  __syncthreads();
  const int n = n0 + tid;
  const u16* qb = qkvvT + ((size_t)b*512 + h*32)*32768 + n;
  const float t2 = temp2[h];
  float s[64];
  #pragma unroll
  for(int p=0;p<64;++p) s[p]=0.f;
  for(int d=0; d<32; ++d){
    float qv = bf2f(qb[(size_t)d*32768]) * liq[d];
    #pragma unroll
    for(int p=0;p<64;++p) s[p] += qv * lkp[d][p];
  }
  float mx = -1e30f;
  #pragma unroll
  for(int p=0;p<64;++p){ s[p] *= t2; mx = fmaxf(mx, s[p]); }
  float sum = 0.f;
  #pragma unroll
  for(int p=0;p<64;++p){ s[p] = __expf(s[p]-mx); sum += s[p]; }
  const float r = 1.0f/sum;
  u16* ob = xsa + (((size_t)b*4 + h)*32)*32768 + n;
  for(int d=0; d<32; ++d){
    float acc = 0.f;
    #pragma unroll
    for(int p=0;p<64;++p) acc += s[p]*lvp[d][p];
    ob[(size_t)d*32768] = f2bf(acc*r);
  }
}

// ============ K_conv v2: fused grouped 3x3x3 conv (fc folded in), out [b][n][128]
// fp32 LDS tile, 2 channels/pass x 8 passes, weights via wave-uniform global loads.
#define CONV_SX 44             // x row stride (floats): idx 0..33 valid, idx=gx+1
#define CONV_SZ 452            // z stride: 10*44 + 12 (bank de-phase)
#define CONV_SC 4520           // channel stride: 10*CONV_SZ
__global__ __launch_bounds__(256,4) void kconv(const u16* __restrict__ qkvvT, const float* __restrict__ W_eff,
                                               const float* __restrict__ bias_eff, u16* __restrict__ convo){
  __shared__ float lf[2*CONV_SC];   // 36,160 B -> 4 blocks/CU
  const int zt = blockIdx.x >> 2, yt = blockIdx.x & 3;
  const int g = blockIdx.y, b = blockIdx.z;
  const int tid = threadIdx.x;
  const int z0 = zt << 3, y0 = yt << 3;
  const int vz = tid >> 5, vy = (tid >> 2) & 7, x0 = (tid & 3) << 3;
  float acc[4][8];
  #pragma unroll
  for(int o=0;o<4;++o)
    #pragma unroll
    for(int xi=0;xi<8;++xi) acc[o][xi] = 0.f;
  const u16* qb = qkvvT + (size_t)b*512*32768;
  // staging decomposition: 200 active threads, one (ch, z-row, y-row) each
  const int sch = tid / 100;
  const int szy = tid - sch*100;
  const int sz  = szy / 10, sy = szy - sz*10;
  const int gz = z0 + sz - 1, gy = y0 + sy - 1;
  const bool srow_ok = (tid < 200) && ((unsigned)gz < 32u) && ((unsigned)gy < 32u);
  float* sdst = &lf[sch*CONV_SC + sz*CONV_SZ + sy*CONV_SX];

  for(int p=0;p<8;++p){
    __syncthreads();   // previous pass compute done
    if(tid < 200){
      float vals[32];
      if(srow_ok){
        const u16* src = qb + (size_t)(((2*p + sch)*32 + g))*32768 + gz*1024 + gy*32;
        #pragma unroll
        for(int q8=0;q8<4;++q8){
          bf16x8 v = *(const bf16x8*)(src + q8*8);
          #pragma unroll
          for(int j=0;j<8;++j) vals[q8*8+j] = bf2f((u16)v[j]);
        }
      } else {
        #pragma unroll
        for(int i=0;i<32;++i) vals[i] = 0.f;
      }
      float2* d2 = (float2*)sdst;
      float2 t0; t0.x = 0.f; t0.y = vals[0]; d2[0] = t0;
      #pragma unroll
      for(int i=0;i<15;++i){ float2 t; t.x = vals[1+2*i]; t.y = vals[2+2*i]; d2[1+i] = t; }
      float2 t1; t1.x = vals[31]; t1.y = 0.f; d2[16] = t1;
    }
    __syncthreads();
    #pragma unroll
    for(int ch=0; ch<2; ++ch){
      const int j = 2*p + ch;
      const float4* Wj = (const float4*)(W_eff + (size_t)((g*16 + j)*27)*4);  // wave-uniform
      #pragma unroll
      for(int kz=0; kz<3; ++kz){
        #pragma unroll
        for(int ky=0; ky<3; ++ky){
          const float* row = &lf[ch*CONV_SC + (vz+kz)*CONV_SZ + (vy+ky)*CONV_SX + x0];
          float4 fa = *(const float4*)(row);
          float4 fb = *(const float4*)(row+4);
          float2 fc = *(const float2*)(row+8);
          float fw[10] = {fa.x,fa.y,fa.z,fa.w, fb.x,fb.y,fb.z,fb.w, fc.x,fc.y};
          #pragma unroll
          for(int kx=0;kx<3;++kx){
            float4 wv = Wj[(kz*3+ky)*3 + kx];
            #pragma unroll
            for(int xi=0;xi<8;++xi){
              float f = fw[xi+kx];
              acc[0][xi] += wv.x*f;
              acc[1][xi] += wv.y*f;
              acc[2][xi] += wv.z*f;
              acc[3][xi] += wv.w*f;
            }
          }
        }
      }
    }
  }
  const float b0 = bias_eff[g*4+0], b1 = bias_eff[g*4+1], b2 = bias_eff[g*4+2], b3 = bias_eff[g*4+3];
  const int nb = (z0+vz)*1024 + (y0+vy)*32 + x0;
  u16* ob = convo + ((size_t)b*32768 + nb)*128 + g*4;
  #pragma unroll
  for(int xi=0;xi<8;++xi){
    unsigned long long pk = (unsigned long long)f2bf(acc[0][xi] + b0)
                          | ((unsigned long long)f2bf(acc[1][xi] + b1) << 16)
                          | ((unsigned long long)f2bf(acc[2][xi] + b2) << 32)
                          | ((unsigned long long)f2bf(acc[3][xi] + b3) << 48);
    *(unsigned long long*)(ob + (size_t)xi*128) = pk;
  }
}

// ============ K6: output assembly (SA gather-GEMM + CA GEMM + conv + rates), fp32 out
#define K6PAD 136
__global__ __launch_bounds__(256) void k6_out(const u16* __restrict__ qkvvT, const u16* __restrict__ xsa,
                                              const u16* __restrict__ conv, const u16* __restrict__ M2,
                                              const u16* __restrict__ Woutb, const float* __restrict__ bout,
                                              const float* __restrict__ bout2, const float* __restrict__ rate,
                                              const float* __restrict__ rate2, float* __restrict__ out){
  __shared__ u16 lA[128*K6PAD];
  const int tile = blockIdx.x;
  const int b  = tile >> 8;
  const int n0 = (tile & 255) << 7;
  const int tid = threadIdx.x;
  const int hh = (n0 >> 8) & 3;   // constant per 128-token tile
  const int dh = n0 >> 10;
  // ---- phase A: stage scrambled x_SA segment (contiguous!) -> lA[tok][c']
  const u16* xseg = xsa + (((size_t)b*4 + hh)*32 + dh)*32768 + ((size_t)(n0 & 255) << 7);
  {
    const int r = tid >> 1, off = (tid & 1) << 6;
    const u16* src = xseg + r*128 + off;
    u16* dst = &lA[r*K6PAD + off];
    #pragma unroll
    for(int q=0;q<8;++q) *(bf16x8*)(dst + q*8) = *(const bf16x8*)(src + q*8);
  }
  __syncthreads();
  const int wave = tid >> 6, lane = tid & 63;
  const int lm = lane & 15, lq = lane >> 4;
  f32x4 accS[2][4] = {};
  #pragma unroll
  for(int ks=0;ks<4;++ks){
    bf16x8 a0 = *(const bf16x8*)(&lA[(wave*32 + lm)*K6PAD + ks*32 + lq*8]);
    bf16x8 a1 = *(const bf16x8*)(&lA[(wave*32 + 16 + lm)*K6PAD + ks*32 + lq*8]);
    #pragma unroll
    for(int nt=0;nt<4;++nt){
      bf16x8 bw = *(const bf16x8*)(Woutb + (nt*16 + lm)*128 + ks*32 + lq*8);
      accS[0][nt] = MFMA16(a0, bw, accS[0][nt]);
      accS[1][nt] = MFMA16(a1, bw, accS[1][nt]);
    }
  }
  __syncthreads();
  // ---- phase B: stage v_CA tile transposed -> lA[tok][c'']
  {
    const int cb = tid >> 4, t8 = (tid & 15) << 3;
    const u16* vb = qkvvT + ((size_t)b*512 + 256)*32768 + n0;
    #pragma unroll
    for(int r2=0;r2<8;++r2){
      int c = cb + (r2<<4);
      bf16x8 v = *(const bf16x8*)(vb + (size_t)c*32768 + t8);
      #pragma unroll
      for(int j=0;j<8;++j) lA[(t8+j)*K6PAD + c] = (u16)v[j];
    }
  }
  __syncthreads();
  f32x4 accC[2][4] = {};
  #pragma unroll
  for(int ks=0;ks<4;++ks){
    bf16x8 a0 = *(const bf16x8*)(&lA[(wave*32 + lm)*K6PAD + ks*32 + lq*8]);
    bf16x8 a1 = *(const bf16x8*)(&lA[(wave*32 + 16 + lm)*K6PAD + ks*32 + lq*8]);
    #pragma unroll
    for(int nt=0;nt<4;++nt){
      bf16x8 bm = *(const bf16x8*)(M2 + ((size_t)b*64 + nt*16 + lm)*128 + ks*32 + lq*8);
      accC[0][nt] = MFMA16(a0, bm, accC[0][nt]);
      accC[1][nt] = MFMA16(a1, bm, accC[1][nt]);
    }
  }
  const float rt = rate[0], rt2 = rate2[0];
  float* ob = out + ((size_t)b*32768 + n0)*128;
  const u16* cbp = conv + ((size_t)b*32768 + n0)*128;
  #pragma unroll
  for(int mt=0;mt<2;++mt){
    #pragma unroll
    for(int r=0;r<4;++r){
      const int tok = wave*32 + mt*16 + lq*4 + r;
      #pragma unroll
      for(int nt=0;nt<4;++nt){
        const int j = nt*16 + lm;
        float sa = accS[mt][nt][r] + bout[j];
        float ca = accC[mt][nt][r] + bout2[j];
        float c1 = bf2f(cbp[(size_t)tok*128 + j]);
        float c2 = bf2f(cbp[(size_t)tok*128 + 64 + j]);
        ob[(size_t)tok*128 + j]      = rt*sa + rt2*c1;
        ob[(size_t)tok*128 + 64 + j] = rt*ca + rt2*c2;
      }
    }
  }
}

extern "C" void kernel_launch(void* const* d_in, const int* in_sizes, int n_in,
                              void* d_out, int out_size, void* d_ws, size_t ws_size,
                              hipStream_t stream){
  const float* x     = (const float*)d_in[0];
  const float* Wq    = (const float*)d_in[1];
  const float* Wfc   = (const float*)d_in[2];
  const float* bfc   = (const float*)d_in[3];
  const float* Wdep  = (const float*)d_in[4];
  const float* bdep  = (const float*)d_in[5];
  const float* WE    = (const float*)d_in[6];
  const float* bE    = (const float*)d_in[7];
  const float* temp  = (const float*)d_in[8];
  const float* temp2 = (const float*)d_in[9];
  const float* rate  = (const float*)d_in[10];
  const float* rate2 = (const float*)d_in[11];
  const float* Wout  = (const float*)d_in[12];
  const float* bout  = (const float*)d_in[13];
  const float* Wout2 = (const float*)d_in[14];
  const float* bout2 = (const float*)d_in[15];
  float* outp = (float*)d_out;

  char* w = (char*)d_ws;
  size_t off = 0;
  auto alloc = [&](size_t bytes)->char*{ char* p = w + off; off += (bytes + 255) & ~(size_t)255; return p; };
  u16*   qkvvT  = (u16*)  alloc((size_t)4*512*32768*2);   // 134 MB, channel-major
  u16*   xsa    = (u16*)  alloc((size_t)4*4*32*32768*2);  // 33.5 MB
  u16*   convb  = (u16*)  alloc((size_t)4*32768*128*2);   // 33.5 MB, token-major
  float* W_eff  = (float*)alloc(55296*4);
  float* biasef = (float*)alloc(128*4);
  float* invn   = (float*)alloc(1024*4);
  float* kp     = (float*)alloc(32768*4);
  float* vp     = (float*)alloc(32768*4);
  float* G      = (float*)alloc(16384*4);
  u16*   M2     = (u16*)  alloc(32768*2);
  u16*   WEb    = (u16*)  alloc((size_t)2097152*2);       // bf16 copies of MFMA weights
  u16*   Wqb    = (u16*)  alloc(65536*2);
  u16*   Woutb  = (u16*)  alloc(8192*2);

  // zero the fp32 atomic-accumulation buffers (kp|vp|G are contiguous)
  hipMemsetAsync(kp, 0, (size_t)(32768+32768+16384)*4, stream);

  kcvt          <<<2048,          256, 0, stream>>>(WE,   WEb,   2097152);
  kcvt          <<<64,            256, 0, stream>>>(Wq,   Wqb,   65536);
  kcvt          <<<8,             256, 0, stream>>>(Wout, Woutb, 8192);
  k1_qkvv       <<<1024,          256, 0, stream>>>(x, Wqb, qkvvT);
  k2_weff       <<<216,           256, 0, stream>>>(Wdep, Wfc, bdep, bfc, W_eff, biasef);
  k2b_norms     <<<1024,          256, 0, stream>>>(qkvvT, invn);
  k3_proj       <<<dim3(32,4,4),  256, 0, stream>>>(qkvvT, WEb, kp, vp);
  k4_gram       <<<dim3(64,4,4),   64, 0, stream>>>(qkvvT, G);
  k4b_softmax_m2<<<16,            256, 0, stream>>>(G, invn, temp, Wout2, M2);
  k5_xsa        <<<dim3(128,4,4), 256, 0, stream>>>(qkvvT, kp, vp, invn, bE, temp2, xsa);
  kconv         <<<dim3(16,32,4), 256, 0, stream>>>(qkvvT, W_eff, biasef, convb);
  k6_out        <<<1024,          256, 0, stream>>>(qkvvT, xsa, convb, M2, Woutb, bout, bout2, rate, rate2, outp);
}

// Round 6
// 630.934 us; speedup vs baseline: 1.9914x; 1.0322x over previous
//
#include <hip/hip_runtime.h>
#include <hip/hip_bf16.h>

typedef unsigned short u16;
typedef __attribute__((ext_vector_type(8))) short bf16x8;
typedef __attribute__((ext_vector_type(4))) float f32x4;

#define MFMA16(a,b,c) __builtin_amdgcn_mfma_f32_16x16x32_bf16((a),(b),(c),0,0,0)

__device__ __forceinline__ float bf2f(u16 u){ union{unsigned int i; float f;} v; v.i=((unsigned int)u)<<16; return v.f; }
__device__ __forceinline__ u16 f2bf(float f){ union{float f; unsigned int i;} v; v.f=f; unsigned int r=v.i+0x7fffu+((v.i>>16)&1u); return (u16)(r>>16); }
__device__ __forceinline__ unsigned int pk2(float a, float b){
  __hip_bfloat162 h = __float22bfloat162_rn(make_float2(a,b));
  union{ __hip_bfloat162 h; unsigned int u; } v; v.h = h; return v.u;
}

// ============ K0: fp32 -> bf16 conversions for the 3 MFMA weights, one launch ====
__global__ __launch_bounds__(256) void kcvt3(const float* __restrict__ WE, u16* __restrict__ WEb,
                                             const float* __restrict__ Wq, u16* __restrict__ Wqb,
                                             const float* __restrict__ Wo, u16* __restrict__ Wob){
  int bid = blockIdx.x;
  const float* src; u16* dst; int base;
  if(bid < 2048){ src = WE; dst = WEb; base = bid*1024; }
  else if(bid < 2112){ src = Wq; dst = Wqb; base = (bid-2048)*1024; }
  else { src = Wo; dst = Wob; base = (bid-2112)*1024; }
  int i = base + threadIdx.x*4;
  float4 v = *(const float4*)(src + i);
  ushort4 o; o.x = f2bf(v.x); o.y = f2bf(v.y); o.z = f2bf(v.z); o.w = f2bf(v.w);
  *(ushort4*)(dst + i) = o;
}

// ================= K1: qkvvT[b][oc][n] = sum_c Wq[oc][c]*x[b][c][n] (MFMA) =========
// A = Wqb (bf16, L2-hot). B = x tile (fp32) transposed+packed into LDS.
// Swizzle is a ROTATION mod 128 within each token row (fixes round-5 overlap bug):
// u16 pos = t*136 + ((swz(t)+c) & 127), swz(t) = ((t>>3)&3)*8.
#define K1PAD 136
__global__ __launch_bounds__(256) void k1_qkvv(const float* __restrict__ x, const u16* __restrict__ Wqb, u16* __restrict__ qkvvT){
  __shared__ u16 lB[128*K1PAD];
  const int tile = blockIdx.x;            // b*256 + token tile
  const int b  = tile >> 8;
  const int n0 = (tile & 255) << 7;
  const int tid = threadIdx.x;
  const float* xb = x + (size_t)b*128*32768;
  {
    const int cb = (tid >> 4) << 1;       // even channel 0..30
    const int m  = tid & 15;
    const int t8 = m << 3;                // 8-token block
    const int swz = (m & 3) << 3;         // rotation amount (u16 units)
    unsigned int* basep = (unsigned int*)lB;
    #pragma unroll
    for(int r=0;r<4;++r){
      const int c = cb + (r<<5);
      const float4* p0 = (const float4*)(xb + (size_t)c*32768 + n0 + t8);
      const float4* p1 = (const float4*)(xb + (size_t)(c+1)*32768 + n0 + t8);
      float4 a0 = p0[0], a1 = p0[1];
      float4 b0 = p1[0], b1 = p1[1];
      const int rot = (swz + c) & 127;    // rotation keeps everything inside the row
      int di = t8*68 + (rot>>1);
      basep[di      ] = pk2(a0.x, b0.x);
      basep[di+  68 ] = pk2(a0.y, b0.y);
      basep[di+ 136 ] = pk2(a0.z, b0.z);
      basep[di+ 204 ] = pk2(a0.w, b0.w);
      basep[di+ 272 ] = pk2(a1.x, b1.x);
      basep[di+ 340 ] = pk2(a1.y, b1.y);
      basep[di+ 408 ] = pk2(a1.z, b1.z);
      basep[di+ 476 ] = pk2(a1.w, b1.w);
    }
  }
  __syncthreads();
  const int wave = tid >> 6, lane = tid & 63;
  const int wm = (wave & 1) << 6;   // oc half
  const int wn = (wave >> 1) << 6;  // token half
  const int lm = lane & 15, lq = lane >> 4;
  u16* outb = qkvvT + (size_t)b*512*32768;
  for(int s=0;s<4;++s){
    const int oc0 = s << 7;
    f32x4 acc[4][4] = {};
    const u16* Arow = Wqb + (oc0 + wm + lm)*128 + lq*8;
    #pragma unroll
    for(int ks=0; ks<4; ++ks){
      bf16x8 af[4], bfr[4];
      #pragma unroll
      for(int mt=0;mt<4;++mt) af[mt] = *(const bf16x8*)(Arow + mt*2048 + ks*32);
      #pragma unroll
      for(int nt=0;nt<4;++nt){
        const int tr = wn + nt*16 + lm;
        const int rot = ((((tr>>3)&3)<<3) + ks*32 + lq*8) & 127;
        bfr[nt] = *(const bf16x8*)(&lB[tr*K1PAD + rot]);
      }
      #pragma unroll
      for(int mt=0;mt<4;++mt)
        #pragma unroll
        for(int nt=0;nt<4;++nt)
          acc[mt][nt] = MFMA16(af[mt], bfr[nt], acc[mt][nt]);
    }
    #pragma unroll
    for(int mt=0;mt<4;++mt){
      const int ocr = oc0 + wm + mt*16 + lq*4;
      #pragma unroll
      for(int nt=0;nt<4;++nt){
        const int n = n0 + wn + nt*16 + lm;
        #pragma unroll
        for(int r=0;r<4;++r) outb[(size_t)(ocr+r)*32768 + n] = f2bf(acc[mt][nt][r]);
      }
    }
  }
}

// ============ K2: fold fc(1x1) into depthwise-grouped conv weights (fp32 in) ======
// W_eff layout: [g 32][j 16][k 27][ol 4] fp32 ; oc = g*4+ol
__global__ void k2_weff(const float* __restrict__ Wdep, const float* __restrict__ Wfc,
                        const float* __restrict__ bdep, const float* __restrict__ bfc,
                        float* __restrict__ W_eff, float* __restrict__ bias_eff){
  int idx = blockIdx.x*256 + threadIdx.x;
  if(idx < 55296){
    int ol = idx & 3;
    int k  = (idx >> 2) % 27;
    int j  = (idx / 108) & 15;
    int g  = idx / 1728;
    int oc = g*4 + ol;
    float s = 0.f;
    for(int o=0;o<16;++o) s += Wdep[(oc*16 + o)*27 + k] * Wfc[o*16 + j];
    W_eff[idx] = s;
  }
  if(idx < 128){
    float s = bdep[idx];
    for(int o=0;o<16;++o){
      float wsum = 0.f;
      for(int k=0;k<27;++k) wsum += Wdep[(idx*16 + o)*27 + k];
      s += wsum * bfc[o];  // b_fc == 0 in this problem (boundary fold vacuous)
    }
    bias_eff[idx] = s;
  }
}

// ============ K2b: inverse l2 norms of q rows (c<128) and k rows (c 128..255) ====
__global__ __launch_bounds__(256) void k2b_norms(const u16* __restrict__ qkvvT, float* __restrict__ invn){
  const int b = blockIdx.x >> 8, c = blockIdx.x & 255;
  const u16* row = qkvvT + ((size_t)b*512 + c)*32768;
  float s = 0.f;
  for(int n = threadIdx.x*8; n < 32768; n += 2048){
    bf16x8 v = *(const bf16x8*)(row + n);
    #pragma unroll
    for(int j=0;j<8;++j){ float f = bf2f((u16)v[j]); s += f*f; }
  }
  for(int off=32; off; off>>=1) s += __shfl_down(s, off, 64);
  __shared__ float wsum[4];
  if((threadIdx.x & 63)==0) wsum[threadIdx.x>>6] = s;
  __syncthreads();
  if(threadIdx.x==0){
    float t = wsum[0]+wsum[1]+wsum[2]+wsum[3];
    invn[blockIdx.x] = 1.0f / fmaxf(sqrtf(t), 1e-12f);
  }
}

// ============ K3: k_proj / v_SA_proj = rows @ W_E^T  (MFMA, K split, atomics) ====
__global__ __launch_bounds__(256) void k3_proj(const u16* __restrict__ qkvvT, const u16* __restrict__ WEb,
                                               float* __restrict__ kp, float* __restrict__ vp){
  const int kc = blockIdx.x;            // K chunk of 1024
  const int b  = blockIdx.y;
  const int ts = blockIdx.z >> 1;       // 0: k, 1: v_SA
  const int rh = (blockIdx.z & 1) << 6; // row half
  const int wave = threadIdx.x >> 6, lane = threadIdx.x & 63;
  const int lm = lane & 15, lq = lane >> 4;
  const int coff = ts ? 384 : 128;
  const u16* Arow = qkvvT + ((size_t)b*512 + coff + rh + wave*16 + lm)*32768 + kc*1024 + lq*8;
  f32x4 acc[4] = {};
  for(int ks=0; ks<32; ++ks){
    bf16x8 af = *(const bf16x8*)(Arow + ks*32);
    #pragma unroll
    for(int nt=0;nt<4;++nt){
      bf16x8 bfr = *(const bf16x8*)(WEb + (size_t)(nt*16 + lm)*32768 + kc*1024 + ks*32 + lq*8);
      acc[nt] = MFMA16(af, bfr, acc[nt]);
    }
  }
  float* out = (ts ? vp : kp) + (size_t)b*128*64;
  const int r0 = rh + wave*16 + lq*4;
  #pragma unroll
  for(int nt=0;nt<4;++nt){
    const int p = nt*16 + lm;
    #pragma unroll
    for(int r=0;r<4;++r) atomicAdd(&out[(r0+r)*64 + p], acc[nt][r]);
  }
}

// ============ K4: Gram G[b,h][d][e] = sum_n q[d,n]k[e,n] (MFMA, K split) =========
__global__ __launch_bounds__(64) void k4_gram(const u16* __restrict__ qkvvT, float* __restrict__ G){
  const int kc = blockIdx.x, b = blockIdx.y, h = blockIdx.z;
  const int lane = threadIdx.x, lm = lane & 15, lq = lane >> 4;
  const u16* qb = qkvvT + ((size_t)b*512 + h*32)*32768 + kc*512 + lq*8;
  const u16* kb = qb + (size_t)128*32768;
  f32x4 acc[2][2] = {};
  for(int ks=0; ks<16; ++ks){
    bf16x8 af[2], bfr[2];
    af[0]  = *(const bf16x8*)(qb + (size_t)lm*32768 + ks*32);
    af[1]  = *(const bf16x8*)(qb + (size_t)(16+lm)*32768 + ks*32);
    bfr[0] = *(const bf16x8*)(kb + (size_t)lm*32768 + ks*32);
    bfr[1] = *(const bf16x8*)(kb + (size_t)(16+lm)*32768 + ks*32);
    #pragma unroll
    for(int mt=0;mt<2;++mt)
      #pragma unroll
      for(int nt=0;nt<2;++nt) acc[mt][nt] = MFMA16(af[mt], bfr[nt], acc[mt][nt]);
  }
  float* Gb = G + (size_t)(b*4 + h)*1024;
  #pragma unroll
  for(int mt=0;mt<2;++mt)
    #pragma unroll
    for(int nt=0;nt<2;++nt)
      #pragma unroll
      for(int r=0;r<4;++r){
        int d = mt*16 + lq*4 + r, e = nt*16 + lm;
        atomicAdd(&Gb[d*32 + e], acc[mt][nt][r]);
      }
}

// ============ K4b: scale+softmax(attn_CA) then M2 = W_out2 * attn_CA =============
__global__ __launch_bounds__(256) void k4b_softmax_m2(const float* __restrict__ G, const float* __restrict__ invn,
                                                      const float* __restrict__ temp, const float* __restrict__ Wout2,
                                                      u16* __restrict__ M2){
  const int b = blockIdx.x >> 2, h = blockIdx.x & 3;
  __shared__ float A[32][33];
  const float* Gb = G + (size_t)(b*4 + h)*1024;
  const float* inb = invn + b*256;
  const float th = temp[h];
  const int tid = threadIdx.x;
  if(tid < 32){
    const int d = tid;
    const float iq = inb[h*32 + d];
    float row[32]; float mx = -1e30f;
    #pragma unroll
    for(int e=0;e<32;++e){
      float v = Gb[d*32+e] * iq * inb[128 + h*32 + e] * th;
      row[e] = v; mx = fmaxf(mx, v);
    }
    float s = 0.f;
    #pragma unroll
    for(int e=0;e<32;++e){ float ee = __expf(row[e]-mx); row[e] = ee; s += ee; }
    const float rs = 1.0f/s;
    #pragma unroll
    for(int e=0;e<32;++e) A[d][e] = row[e]*rs;
  }
  __syncthreads();
  for(int o = tid; o < 2048; o += 256){
    const int j = o >> 5, e = o & 31;
    float s = 0.f;
    #pragma unroll
    for(int d=0;d<32;++d) s += Wout2[j*128 + h*32 + d] * A[d][e];
    M2[((size_t)b*64 + j)*128 + h*32 + e] = f2bf(s);
  }
}

// ============ K5: spatial (Linformer) attention per token -> xsa[b][h][d][n] =====
__global__ __launch_bounds__(256) void k5_xsa(const u16* __restrict__ qkvvT, const float* __restrict__ kp,
                                              const float* __restrict__ vp, const float* __restrict__ invn,
                                              const float* __restrict__ bE, const float* __restrict__ temp2,
                                              u16* __restrict__ xsa){
  const int b = blockIdx.z, h = blockIdx.y, n0 = blockIdx.x*256;
  __shared__ float lkp[32][64], lvp[32][64], liq[32];
  const int tid = threadIdx.x;
  for(int o = tid; o < 2048; o += 256){
    int d = o >> 6, p = o & 63;
    float be = bE[p];
    size_t base = ((size_t)b*128 + h*32 + d)*64 + p;
    lkp[d][p] = kp[base] + be;
    lvp[d][p] = vp[base] + be;
  }
  if(tid < 32) liq[tid] = invn[b*256 + h*32 + tid];
  __syncthreads();
  const int n = n0 + tid;
  const u16* qb = qkvvT + ((size_t)b*512 + h*32)*32768 + n;
  const float t2 = temp2[h];
  float s[64];
  #pragma unroll
  for(int p=0;p<64;++p) s[p]=0.f;
  for(int d=0; d<32; ++d){
    float qv = bf2f(qb[(size_t)d*32768]) * liq[d];
    #pragma unroll
    for(int p=0;p<64;++p) s[p] += qv * lkp[d][p];
  }
  float mx = -1e30f;
  #pragma unroll
  for(int p=0;p<64;++p){ s[p] *= t2; mx = fmaxf(mx, s[p]); }
  float sum = 0.f;
  #pragma unroll
  for(int p=0;p<64;++p){ s[p] = __expf(s[p]-mx); sum += s[p]; }
  const float r = 1.0f/sum;
  u16* ob = xsa + (((size_t)b*4 + h)*32)*32768 + n;
  for(int d=0; d<32; ++d){
    float acc = 0.f;
    #pragma unroll
    for(int p=0;p<64;++p) acc += s[p]*lvp[d][p];
    ob[(size_t)d*32768] = f2bf(acc*r);
  }
}

// ============ K_conv v3: fused grouped 3x3x3 conv, z-pair per thread =============
// 1 channel/pass x 16 passes; LDS fp32 tile z18 x y10 x x36 (25.9 KB);
// row stride 36 (=4 mod 32): b128 window reads 2-way/free; weights via s_load.
#define CSX 36
#define CSZ 360            // 10*CSX
__global__ __launch_bounds__(256,4) void kconv(const u16* __restrict__ qkvvT, const float* __restrict__ W_eff,
                                               const float* __restrict__ bias_eff, u16* __restrict__ convo){
  __shared__ float lf[18*CSZ];   // 25,920 B
  const int zt = blockIdx.x >> 2, yt = blockIdx.x & 3;
  const int g = blockIdx.y, b = blockIdx.z;
  const int tid = threadIdx.x;
  const int z0 = zt << 4, y0 = yt << 3;
  const int lz = (tid >> 5) << 1;         // output z pair base (0..14)
  const int vy = (tid >> 2) & 7;
  const int x0 = (tid & 3) << 3;
  float acc[2][4][8];
  #pragma unroll
  for(int o=0;o<2;++o)
    #pragma unroll
    for(int oc=0;oc<4;++oc)
      #pragma unroll
      for(int xi=0;xi<8;++xi) acc[o][oc][xi] = 0.f;
  const u16* qb = qkvvT + (size_t)b*512*32768;
  // staging: threads 0..179 each own one (z-row, y-row)
  const int sz = tid / 10, sy = tid - sz*10;
  const int gz = z0 + sz - 1, gy = y0 + sy - 1;
  const bool srow_ok = (tid < 180) && ((unsigned)gz < 32u) && ((unsigned)gy < 32u);
  float2* d2 = (float2*)&lf[sz*CSZ + sy*CSX];
  const float* Wgbase = W_eff + (size_t)(g*16)*108;

  for(int p=0;p<16;++p){
    __syncthreads();   // previous pass compute done
    if(tid < 180){
      if(srow_ok){
        const u16* src = qb + ((size_t)(p*32 + g))*32768 + gz*1024 + gy*32;
        float carry = 0.f;
        #pragma unroll
        for(int q=0;q<4;++q){
          bf16x8 v = *(const bf16x8*)(src + q*8);
          float w0=bf2f((u16)v[0]), w1=bf2f((u16)v[1]), w2=bf2f((u16)v[2]), w3=bf2f((u16)v[3]);
          float w4=bf2f((u16)v[4]), w5=bf2f((u16)v[5]), w6=bf2f((u16)v[6]), w7=bf2f((u16)v[7]);
          d2[q*4+0] = make_float2(carry, w0);
          d2[q*4+1] = make_float2(w1, w2);
          d2[q*4+2] = make_float2(w3, w4);
          d2[q*4+3] = make_float2(w5, w6);
          carry = w7;
        }
        d2[16] = make_float2(carry, 0.f);
      } else {
        #pragma unroll
        for(int i=0;i<17;++i) d2[i] = make_float2(0.f, 0.f);
      }
    }
    __syncthreads();
    const float* Wg = Wgbase + p*108;    // [kz3][ky3][kx3][oc4], wave-uniform
    #pragma unroll
    for(int dy=0;dy<3;++dy){
      #pragma unroll
      for(int dz=0;dz<4;++dz){
        const float* row = &lf[(lz+dz)*CSZ + (vy+dy)*CSX + x0];
        float4 fa = *(const float4*)(row);
        float4 fb = *(const float4*)(row+4);
        float2 fc = *(const float2*)(row+8);
        float fw[10] = {fa.x,fa.y,fa.z,fa.w, fb.x,fb.y,fb.z,fb.w, fc.x,fc.y};
        if(dz < 3){
          const float* Wb = Wg + (dz*3+dy)*12;
          #pragma unroll
          for(int kx=0;kx<3;++kx){
            float4 wv = *(const float4*)(Wb + kx*4);
            #pragma unroll
            for(int xi=0;xi<8;++xi){
              float f = fw[xi+kx];
              acc[0][0][xi] += wv.x*f; acc[0][1][xi] += wv.y*f;
              acc[0][2][xi] += wv.z*f; acc[0][3][xi] += wv.w*f;
            }
          }
        }
        if(dz > 0){
          const float* Wb = Wg + ((dz-1)*3+dy)*12;
          #pragma unroll
          for(int kx=0;kx<3;++kx){
            float4 wv = *(const float4*)(Wb + kx*4);
            #pragma unroll
            for(int xi=0;xi<8;++xi){
              float f = fw[xi+kx];
              acc[1][0][xi] += wv.x*f; acc[1][1][xi] += wv.y*f;
              acc[1][2][xi] += wv.z*f; acc[1][3][xi] += wv.w*f;
            }
          }
        }
      }
    }
  }
  const float4 bi = *(const float4*)(bias_eff + g*4);  // wave-uniform -> s_load
  #pragma unroll
  for(int o=0;o<2;++o){
    const int nb = (z0 + lz + o)*1024 + (y0+vy)*32 + x0;
    u16* ob = convo + ((size_t)b*32768 + nb)*128 + g*4;
    #pragma unroll
    for(int xi=0;xi<8;++xi){
      unsigned long long pk = (unsigned long long)f2bf(acc[o][0][xi] + bi.x)
                            | ((unsigned long long)f2bf(acc[o][1][xi] + bi.y) << 16)
                            | ((unsigned long long)f2bf(acc[o][2][xi] + bi.z) << 32)
                            | ((unsigned long long)f2bf(acc[o][3][xi] + bi.w) << 48);
      *(unsigned long long*)(ob + (size_t)xi*128) = pk;
    }
  }
}

// ============ K6: output assembly (SA gather-GEMM + CA GEMM + conv + rates), fp32 out
#define K6PAD 136
__global__ __launch_bounds__(256) void k6_out(const u16* __restrict__ qkvvT, const u16* __restrict__ xsa,
                                              const u16* __restrict__ conv, const u16* __restrict__ M2,
                                              const u16* __restrict__ Woutb, const float* __restrict__ bout,
                                              const float* __restrict__ bout2, const float* __restrict__ rate,
                                              const float* __restrict__ rate2, float* __restrict__ out){
  __shared__ u16 lA[128*K6PAD];
  const int tile = blockIdx.x;
  const int b  = tile >> 8;
  const int n0 = (tile & 255) << 7;
  const int tid = threadIdx.x;
  const int hh = (n0 >> 8) & 3;   // constant per 128-token tile
  const int dh = n0 >> 10;
  // ---- phase A: stage scrambled x_SA segment (contiguous!) -> lA[tok][c']
  const u16* xseg = xsa + (((size_t)b*4 + hh)*32 + dh)*32768 + ((size_t)(n0 & 255) << 7);
  {
    const int r = tid >> 1, off = (tid & 1) << 6;
    const u16* src = xseg + r*128 + off;
    u16* dst = &lA[r*K6PAD + off];
    #pragma unroll
    for(int q=0;q<8;++q) *(bf16x8*)(dst + q*8) = *(const bf16x8*)(src + q*8);
  }
  __syncthreads();
  const int wave = tid >> 6, lane = tid & 63;
  const int lm = lane & 15, lq = lane >> 4;
  f32x4 accS[2][4] = {};
  #pragma unroll
  for(int ks=0;ks<4;++ks){
    bf16x8 a0 = *(const bf16x8*)(&lA[(wave*32 + lm)*K6PAD + ks*32 + lq*8]);
    bf16x8 a1 = *(const bf16x8*)(&lA[(wave*32 + 16 + lm)*K6PAD + ks*32 + lq*8]);
    #pragma unroll
    for(int nt=0;nt<4;++nt){
      bf16x8 bw = *(const bf16x8*)(Woutb + (nt*16 + lm)*128 + ks*32 + lq*8);
      accS[0][nt] = MFMA16(a0, bw, accS[0][nt]);
      accS[1][nt] = MFMA16(a1, bw, accS[1][nt]);
    }
  }
  __syncthreads();
  // ---- phase B: stage v_CA tile transposed -> lA[tok][c'']
  {
    const int cb = tid >> 4, t8 = (tid & 15) << 3;
    const u16* vb = qkvvT + ((size_t)b*512 + 256)*32768 + n0;
    #pragma unroll
    for(int r2=0;r2<8;++r2){
      int c = cb + (r2<<4);
      bf16x8 v = *(const bf16x8*)(vb + (size_t)c*32768 + t8);
      #pragma unroll
      for(int j=0;j<8;++j) lA[(t8+j)*K6PAD + c] = (u16)v[j];
    }
  }
  __syncthreads();
  f32x4 accC[2][4] = {};
  #pragma unroll
  for(int ks=0;ks<4;++ks){
    bf16x8 a0 = *(const bf16x8*)(&lA[(wave*32 + lm)*K6PAD + ks*32 + lq*8]);
    bf16x8 a1 = *(const bf16x8*)(&lA[(wave*32 + 16 + lm)*K6PAD + ks*32 + lq*8]);
    #pragma unroll
    for(int nt=0;nt<4;++nt){
      bf16x8 bm = *(const bf16x8*)(M2 + ((size_t)b*64 + nt*16 + lm)*128 + ks*32 + lq*8);
      accC[0][nt] = MFMA16(a0, bm, accC[0][nt]);
      accC[1][nt] = MFMA16(a1, bm, accC[1][nt]);
    }
  }
  const float rt = rate[0], rt2 = rate2[0];
  float* ob = out + ((size_t)b*32768 + n0)*128;
  const u16* cbp = conv + ((size_t)b*32768 + n0)*128;
  #pragma unroll
  for(int mt=0;mt<2;++mt){
    #pragma unroll
    for(int r=0;r<4;++r){
      const int tok = wave*32 + mt*16 + lq*4 + r;
      #pragma unroll
      for(int nt=0;nt<4;++nt){
        const int j = nt*16 + lm;
        float sa = accS[mt][nt][r] + bout[j];
        float ca = accC[mt][nt][r] + bout2[j];
        float c1 = bf2f(cbp[(size_t)tok*128 + j]);
        float c2 = bf2f(cbp[(size_t)tok*128 + 64 + j]);
        ob[(size_t)tok*128 + j]      = rt*sa + rt2*c1;
        ob[(size_t)tok*128 + 64 + j] = rt*ca + rt2*c2;
      }
    }
  }
}

extern "C" void kernel_launch(void* const* d_in, const int* in_sizes, int n_in,
                              void* d_out, int out_size, void* d_ws, size_t ws_size,
                              hipStream_t stream){
  const float* x     = (const float*)d_in[0];
  const float* Wq    = (const float*)d_in[1];
  const float* Wfc   = (const float*)d_in[2];
  const float* bfc   = (const float*)d_in[3];
  const float* Wdep  = (const float*)d_in[4];
  const float* bdep  = (const float*)d_in[5];
  const float* WE    = (const float*)d_in[6];
  const float* bE    = (const float*)d_in[7];
  const float* temp  = (const float*)d_in[8];
  const float* temp2 = (const float*)d_in[9];
  const float* rate  = (const float*)d_in[10];
  const float* rate2 = (const float*)d_in[11];
  const float* Wout  = (const float*)d_in[12];
  const float* bout  = (const float*)d_in[13];
  const float* Wout2 = (const float*)d_in[14];
  const float* bout2 = (const float*)d_in[15];
  float* outp = (float*)d_out;

  char* w = (char*)d_ws;
  size_t off = 0;
  auto alloc = [&](size_t bytes)->char*{ char* p = w + off; off += (bytes + 255) & ~(size_t)255; return p; };
  u16*   qkvvT  = (u16*)  alloc((size_t)4*512*32768*2);   // 134 MB, channel-major
  u16*   xsa    = (u16*)  alloc((size_t)4*4*32*32768*2);  // 33.5 MB
  u16*   convb  = (u16*)  alloc((size_t)4*32768*128*2);   // 33.5 MB, token-major
  float* W_eff  = (float*)alloc(55296*4);
  float* biasef = (float*)alloc(128*4);
  float* invn   = (float*)alloc(1024*4);
  float* kp     = (float*)alloc(32768*4);
  float* vp     = (float*)alloc(32768*4);
  float* G      = (float*)alloc(16384*4);
  u16*   M2     = (u16*)  alloc(32768*2);
  u16*   WEb    = (u16*)  alloc((size_t)2097152*2);       // bf16 copies of MFMA weights
  u16*   Wqb    = (u16*)  alloc(65536*2);
  u16*   Woutb  = (u16*)  alloc(8192*2);

  // zero the fp32 atomic-accumulation buffers (kp|vp|G are contiguous)
  hipMemsetAsync(kp, 0, (size_t)(32768+32768+16384)*4, stream);

  kcvt3         <<<2120,          256, 0, stream>>>(WE, WEb, Wq, Wqb, Wout, Woutb);
  k1_qkvv       <<<1024,          256, 0, stream>>>(x, Wqb, qkvvT);
  k2_weff       <<<216,           256, 0, stream>>>(Wdep, Wfc, bdep, bfc, W_eff, biasef);
  k2b_norms     <<<1024,          256, 0, stream>>>(qkvvT, invn);
  k3_proj       <<<dim3(32,4,4),  256, 0, stream>>>(qkvvT, WEb, kp, vp);
  k4_gram       <<<dim3(64,4,4),   64, 0, stream>>>(qkvvT, G);
  k4b_softmax_m2<<<16,            256, 0, stream>>>(G, invn, temp, Wout2, M2);
  k5_xsa        <<<dim3(128,4,4), 256, 0, stream>>>(qkvvT, kp, vp, invn, bE, temp2, xsa);
  kconv         <<<dim3(8,32,4),  256, 0, stream>>>(qkvvT, W_eff, biasef, convb);
  k6_out        <<<1024,          256, 0, stream>>>(qkvvT, xsa, convb, M2, Woutb, bout, bout2, rate, rate2, outp);
}